// Round 1
// baseline (209.199 us; speedup 1.0000x reference)
//
#include <hip/hip_runtime.h>

#define H 200
#define D 768
#define BATCH 4
#define S 512
#define M (BATCH*S)   // 2048 rows total across batch
#define RPB 8         // rows per block in projection-style GEMMs
#define TS 32         // output tile for scores kernel
#define LDH 201       // padded LDS stride (gcd(9,32)=1 -> conflict-free)

// ---------------------------------------------------------------------------
// Kernel 1: V[i,j] = sum_o W_down[o] * U[o,i,j]
// o-split 8 ways for parallelism (1256 blocks); V pre-zeroed via memsetAsync.
// ---------------------------------------------------------------------------
__global__ void reduceU(const float* __restrict__ U, const float* __restrict__ Wd,
                        float* __restrict__ V) {
    int idx = blockIdx.x * blockDim.x + threadIdx.x;   // i*H + j, contiguous
    if (idx >= H * H) return;
    int o0 = blockIdx.y * 25;
    float acc = 0.f;
    #pragma unroll 5
    for (int o = o0; o < o0 + 25; ++o)
        acc += Wd[o] * U[(size_t)o * H * H + idx];     // coalesced over idx
    atomicAdd(&V[idx], acc);
}

// ---------------------------------------------------------------------------
// Kernel 2: head = relu(x@W_head + b_head), tail = relu(x@W_tail + b_tail)
// Block handles 8 rows; x rows staged in LDS (broadcast reads); thread j owns
// output column j for all 8 rows of both matrices.
// ---------------------------------------------------------------------------
__global__ void proj(const float* __restrict__ x,
                     const float* __restrict__ Wh, const float* __restrict__ bh,
                     const float* __restrict__ Wt, const float* __restrict__ bt,
                     float* __restrict__ head, float* __restrict__ tail) {
    __shared__ float xs[RPB][D];                       // 24 KB
    int r0 = blockIdx.x * RPB;
    for (int i = threadIdx.x; i < RPB * D; i += 256)
        xs[i / D][i % D] = x[(size_t)(r0 + i / D) * D + (i % D)];
    __syncthreads();
    int j = threadIdx.x;
    if (j < H) {
        float acch[RPB], acct[RPB];
        #pragma unroll
        for (int r = 0; r < RPB; ++r) { acch[r] = bh[j]; acct[r] = bt[j]; }
        for (int d = 0; d < D; ++d) {
            float wh = Wh[d * H + j];                  // coalesced over j
            float wt = Wt[d * H + j];
            #pragma unroll
            for (int r = 0; r < RPB; ++r) {
                acch[r] += xs[r][d] * wh;              // LDS broadcast
                acct[r] += xs[r][d] * wt;
            }
        }
        #pragma unroll
        for (int r = 0; r < RPB; ++r) {
            head[(size_t)(r0 + r) * H + j] = fmaxf(acch[r], 0.f);
            tail[(size_t)(r0 + r) * H + j] = fmaxf(acct[r], 0.f);
        }
    }
}

// ---------------------------------------------------------------------------
// Kernel 3: hv = head @ V   ([2048,200] @ [200,200])
// ---------------------------------------------------------------------------
__global__ void hvk(const float* __restrict__ head, const float* __restrict__ V,
                    float* __restrict__ hv) {
    __shared__ float hs[RPB][H];                       // 6.4 KB
    int r0 = blockIdx.x * RPB;
    for (int i = threadIdx.x; i < RPB * H; i += 256)
        hs[i / H][i % H] = head[(size_t)(r0 + i / H) * H + (i % H)];
    __syncthreads();
    int j = threadIdx.x;
    if (j < H) {
        float acc[RPB] = {};
        for (int k = 0; k < H; ++k) {
            float v = V[k * H + j];                    // coalesced over j
            #pragma unroll
            for (int r = 0; r < RPB; ++r) acc[r] += hs[r][k] * v;
        }
        #pragma unroll
        for (int r = 0; r < RPB; ++r)
            hv[(size_t)(r0 + r) * H + j] = acc[r];
    }
}

// ---------------------------------------------------------------------------
// Kernel 4: out[b,x,y] = (dot(hv[b,x,:], tail[b,y,:]) + b_down) / sqrt(200)
// 32x32 output tile, 2x2 per thread. x-rows bound to ty (broadcast LDS reads),
// y-cols bound to tx (conflict-free via LDH=201, coalesced stores).
// ---------------------------------------------------------------------------
__global__ void scores_k(const float* __restrict__ hv, const float* __restrict__ tail,
                         const float* __restrict__ bd, float* __restrict__ out) {
    __shared__ float as[TS][LDH];                      // hv slab   (25.7 KB)
    __shared__ float bs[TS][LDH];                      // tail slab (25.7 KB)
    int b  = blockIdx.z;
    int x0 = blockIdx.x * TS;
    int y0 = blockIdx.y * TS;
    const float* A  = hv   + (size_t)b * S * H;
    const float* Bm = tail + (size_t)b * S * H;
    int tid = threadIdx.y * 16 + threadIdx.x;
    for (int i = tid; i < TS * H; i += 256) {
        int r = i / H, c = i % H;
        as[r][c] = A[(size_t)(x0 + r) * H + c];
        bs[r][c] = Bm[(size_t)(y0 + r) * H + c];
    }
    __syncthreads();
    int tx = threadIdx.x, ty = threadIdx.y;
    float acc[2][2] = {};
    for (int k = 0; k < H; ++k) {
        float a0 = as[ty     ][k];                     // x-rows: ty, ty+16
        float a1 = as[ty + 16][k];
        float b0 = bs[tx     ][k];                     // y-cols: tx, tx+16
        float b1 = bs[tx + 16][k];
        acc[0][0] += a0 * b0; acc[0][1] += a0 * b1;
        acc[1][0] += a1 * b0; acc[1][1] += a1 * b1;
    }
    float bias = bd[0];
    const float scale = 0.07071067811865475f;          // 1/sqrt(200)
    #pragma unroll
    for (int i = 0; i < 2; ++i) {
        int xx = x0 + ty + 16 * i;
        #pragma unroll
        for (int j = 0; j < 2; ++j) {
            int yy = y0 + tx + 16 * j;                 // coalesced over tx
            out[((size_t)b * S + xx) * S + yy] = (acc[i][j] + bias) * scale;
        }
    }
}

extern "C" void kernel_launch(void* const* d_in, const int* in_sizes, int n_in,
                              void* d_out, int out_size, void* d_ws, size_t ws_size,
                              hipStream_t stream) {
    const float* x  = (const float*)d_in[0];
    const float* Wh = (const float*)d_in[1];
    const float* bh = (const float*)d_in[2];
    const float* Wt = (const float*)d_in[3];
    const float* bt = (const float*)d_in[4];
    const float* U  = (const float*)d_in[5];
    const float* Wd = (const float*)d_in[6];
    const float* bd = (const float*)d_in[7];
    float* out = (float*)d_out;

    // workspace layout (fp32): V[200*200] | head[2048*200] | tail[2048*200] | hv[2048*200]
    float* V    = (float*)d_ws;
    float* head = V    + H * H;
    float* tailp= head + (size_t)M * H;
    float* hv   = tailp+ (size_t)M * H;

    hipMemsetAsync(V, 0, H * H * sizeof(float), stream);  // capture-safe
    reduceU<<<dim3((H * H + 255) / 256, 8), 256, 0, stream>>>(U, Wd, V);
    proj   <<<M / RPB, 256, 0, stream>>>(x, Wh, bh, Wt, bt, head, tailp);
    hvk    <<<M / RPB, 256, 0, stream>>>(head, V, hv);
    scores_k<<<dim3(S / TS, S / TS, BATCH), dim3(16, 16), 0, stream>>>(hv, tailp, bd, out);
}

// Round 2
// 130.212 us; speedup vs baseline: 1.6066x; 1.6066x over previous
//
#include <hip/hip_runtime.h>

#define H 200
#define D 768
#define BATCH 4
#define S 512
#define M (BATCH*S)     // 2048
#define KP 224          // H padded to mult of 32 (MFMA K-step)
#define NP 208          // H padded to mult of 16 (hv N-dim)
#define NCAT 400        // head|tail concatenated output cols
#define OG 8            // o-split groups in reduceU

typedef __attribute__((ext_vector_type(8))) short bf16x8;   // 8 bf16 (4 VGPRs)
typedef __attribute__((ext_vector_type(4))) float f32x4;
typedef unsigned short us;

__device__ inline us f2bf(float f) {            // round-to-nearest-even fp32->bf16
    union { float f; unsigned u; } v; v.f = f;
    return (us)((v.u + 0x7FFF + ((v.u >> 16) & 1)) >> 16);
}

// ---------------------------------------------------------------------------
// Conversions
// ---------------------------------------------------------------------------
__global__ void cvt_x(const float4* __restrict__ x4, ushort4* __restrict__ xb4) {
    int t = blockIdx.x * 256 + threadIdx.x;     // M*D/4 = 393216 exact
    float4 v = x4[t];
    ushort4 o; o.x = f2bf(v.x); o.y = f2bf(v.y); o.z = f2bf(v.z); o.w = f2bf(v.w);
    xb4[t] = o;
}

// Wcb[n][k] = W{h|t}[k][n]  (bf16, [NCAT,D] row-major = B^T layout for MFMA)
__global__ void cvt_W(const float* __restrict__ Wh, const float* __restrict__ Wt,
                      us* __restrict__ Wcb) {
    int id = blockIdx.x * 256 + threadIdx.x;    // n*D + k
    if (id >= NCAT * D) return;
    int n = id / D, k = id % D;
    float v = (n < H) ? Wh[k * H + n] : Wt[k * H + (n - H)];
    Wcb[id] = f2bf(v);
}

// ---------------------------------------------------------------------------
// V[i,j] = sum_o Wd[o]*U[o,i,j]; partials over 8 o-groups (no atomics)
// ---------------------------------------------------------------------------
__global__ void reduceU_part(const float4* __restrict__ U4, const float* __restrict__ Wd,
                             float4* __restrict__ P4) {
    int t = blockIdx.x * 256 + threadIdx.x;     // float4 index into [H*H]
    if (t >= H * H / 4) return;                 // 10000
    int g = blockIdx.y;
    float4 acc = make_float4(0.f, 0.f, 0.f, 0.f);
    int o0 = g * (H / OG);
    #pragma unroll 5
    for (int o = o0; o < o0 + H / OG; ++o) {
        float w = Wd[o];
        float4 u = U4[o * (H * H / 4) + t];     // coalesced, HBM-bound
        acc.x += w * u.x; acc.y += w * u.y; acc.z += w * u.z; acc.w += w * u.w;
    }
    P4[g * (H * H / 4) + t] = acc;
}

// VTb[n][k] = sum_g P[g][k*H+n], zero-padded to [NP,KP]  (V^T, bf16)
__global__ void cvt_V(const float* __restrict__ P, us* __restrict__ VTb) {
    int id = blockIdx.x * 256 + threadIdx.x;
    if (id >= NP * KP) return;
    int n = id / KP, k = id % KP;
    float s = 0.f;
    if (n < H && k < H) {
        #pragma unroll
        for (int g = 0; g < OG; ++g) s += P[g * H * H + k * H + n];
    }
    VTb[id] = f2bf(s);
}

// ---------------------------------------------------------------------------
// proj: C[2048,400] = xb[2048,768] @ Wcb^T; relu(+bias); split into headb|tailb
// One wave per 32x16 tile. A,B frags loaded 16B/lane direct from global (L2).
// ---------------------------------------------------------------------------
__global__ __launch_bounds__(64) void proj_mfma(
        const us* __restrict__ xb, const us* __restrict__ Wcb,
        const float* __restrict__ bh, const float* __restrict__ bt,
        us* __restrict__ headb, us* __restrict__ tailb) {
    int lane = threadIdx.x, quad = lane >> 4, col = lane & 15;
    int m0 = blockIdx.x * 32, n0 = blockIdx.y * 16;
    const bf16x8* A0 = (const bf16x8*)(xb + (m0 + col) * D + quad * 8);
    const bf16x8* A1 = (const bf16x8*)(xb + (m0 + 16 + col) * D + quad * 8);
    const bf16x8* Bp = (const bf16x8*)(Wcb + (n0 + col) * D + quad * 8);
    f32x4 acc0 = {0.f,0.f,0.f,0.f}, acc1 = {0.f,0.f,0.f,0.f};
    #pragma unroll 4
    for (int kk = 0; kk < D / 32; ++kk) {       // 24 iters; 4 bf16x8 per k-step row
        bf16x8 a0 = A0[kk * 4];
        bf16x8 a1 = A1[kk * 4];
        bf16x8 b  = Bp[kk * 4];
        acc0 = __builtin_amdgcn_mfma_f32_16x16x32_bf16(a0, b, acc0, 0, 0, 0);
        acc1 = __builtin_amdgcn_mfma_f32_16x16x32_bf16(a1, b, acc1, 0, 0, 0);
    }
    int n = n0 + col;
    float bias; us* dst; int nn;
    if (n < H) { bias = bh[n];     dst = headb; nn = n; }
    else       { bias = bt[n - H]; dst = tailb; nn = n - H; }
    #pragma unroll
    for (int r = 0; r < 4; ++r) {               // D row = quad*4+r, col = lane&15
        int ma = m0 + quad * 4 + r;
        dst[ma * KP + nn]        = f2bf(fmaxf(acc0[r] + bias, 0.f));
        dst[(ma + 16) * KP + nn] = f2bf(fmaxf(acc1[r] + bias, 0.f));
    }
}

// ---------------------------------------------------------------------------
// hv[2048,208] = headb[2048,224] @ VTb[208,224]^T   (K=224, zero-padded)
// ---------------------------------------------------------------------------
__global__ __launch_bounds__(64) void hv_mfma(
        const us* __restrict__ headb, const us* __restrict__ VTb,
        us* __restrict__ hvb) {
    int lane = threadIdx.x, quad = lane >> 4, col = lane & 15;
    int m0 = blockIdx.x * 32, n0 = blockIdx.y * 16;
    const bf16x8* A0 = (const bf16x8*)(headb + (m0 + col) * KP + quad * 8);
    const bf16x8* A1 = (const bf16x8*)(headb + (m0 + 16 + col) * KP + quad * 8);
    const bf16x8* Bp = (const bf16x8*)(VTb + (n0 + col) * KP + quad * 8);
    f32x4 acc0 = {0.f,0.f,0.f,0.f}, acc1 = {0.f,0.f,0.f,0.f};
    #pragma unroll
    for (int kk = 0; kk < KP / 32; ++kk) {      // 7 iters
        bf16x8 a0 = A0[kk * 4];
        bf16x8 a1 = A1[kk * 4];
        bf16x8 b  = Bp[kk * 4];
        acc0 = __builtin_amdgcn_mfma_f32_16x16x32_bf16(a0, b, acc0, 0, 0, 0);
        acc1 = __builtin_amdgcn_mfma_f32_16x16x32_bf16(a1, b, acc1, 0, 0, 0);
    }
    int n = n0 + col;                           // < 208; cols 200..207 are exact 0
    #pragma unroll
    for (int r = 0; r < 4; ++r) {
        int ma = m0 + quad * 4 + r;
        hvb[ma * KP + n]        = f2bf(acc0[r]);
        hvb[(ma + 16) * KP + n] = f2bf(acc1[r]);
    }
}

// ---------------------------------------------------------------------------
// scores[b,x,y] = (hv[b,x,:] . tail[b,y,:] + b_down)/sqrt(200); 32x32 per wave
// ---------------------------------------------------------------------------
__global__ __launch_bounds__(64) void scores_mfma(
        const us* __restrict__ hvb, const us* __restrict__ tailb,
        const float* __restrict__ bd, float* __restrict__ out) {
    int lane = threadIdx.x, quad = lane >> 4, col = lane & 15;
    int b = blockIdx.z;
    int m0 = blockIdx.x * 32, n0 = blockIdx.y * 32;
    const us* A  = hvb   + b * S * KP;
    const us* Bm = tailb + b * S * KP;
    const bf16x8* A0 = (const bf16x8*)(A  + (m0 + col) * KP + quad * 8);
    const bf16x8* A1 = (const bf16x8*)(A  + (m0 + 16 + col) * KP + quad * 8);
    const bf16x8* B0 = (const bf16x8*)(Bm + (n0 + col) * KP + quad * 8);
    const bf16x8* B1 = (const bf16x8*)(Bm + (n0 + 16 + col) * KP + quad * 8);
    f32x4 a00 = {0.f,0.f,0.f,0.f}, a01 = {0.f,0.f,0.f,0.f};
    f32x4 a10 = {0.f,0.f,0.f,0.f}, a11 = {0.f,0.f,0.f,0.f};
    #pragma unroll
    for (int kk = 0; kk < KP / 32; ++kk) {      // 7 iters
        bf16x8 a0 = A0[kk * 4];
        bf16x8 a1 = A1[kk * 4];
        bf16x8 b0 = B0[kk * 4];
        bf16x8 b1 = B1[kk * 4];
        a00 = __builtin_amdgcn_mfma_f32_16x16x32_bf16(a0, b0, a00, 0, 0, 0);
        a01 = __builtin_amdgcn_mfma_f32_16x16x32_bf16(a0, b1, a01, 0, 0, 0);
        a10 = __builtin_amdgcn_mfma_f32_16x16x32_bf16(a1, b0, a10, 0, 0, 0);
        a11 = __builtin_amdgcn_mfma_f32_16x16x32_bf16(a1, b1, a11, 0, 0, 0);
    }
    float bias = bd[0];
    const float scale = 0.07071067811865475f;   // 1/sqrt(200)
    float* outb = out + b * S * S;
    #pragma unroll
    for (int r = 0; r < 4; ++r) {
        int ma = m0 + quad * 4 + r, mb = ma + 16;
        outb[ma * S + n0 + col]      = (a00[r] + bias) * scale;
        outb[ma * S + n0 + 16 + col] = (a01[r] + bias) * scale;
        outb[mb * S + n0 + col]      = (a10[r] + bias) * scale;
        outb[mb * S + n0 + 16 + col] = (a11[r] + bias) * scale;
    }
}

extern "C" void kernel_launch(void* const* d_in, const int* in_sizes, int n_in,
                              void* d_out, int out_size, void* d_ws, size_t ws_size,
                              hipStream_t stream) {
    const float* x  = (const float*)d_in[0];
    const float* Wh = (const float*)d_in[1];
    const float* bh = (const float*)d_in[2];
    const float* Wt = (const float*)d_in[3];
    const float* bt = (const float*)d_in[4];
    const float* U  = (const float*)d_in[5];
    const float* Wd = (const float*)d_in[6];
    const float* bd = (const float*)d_in[7];
    float* out = (float*)d_out;

    // ws layout (bf16 elements): xb | Wcb | VTb | hvb | headb | tailb  (~6.6 MB)
    us* xb    = (us*)d_ws;
    us* Wcb   = xb  + (size_t)M * D;
    us* VTb   = Wcb + (size_t)NCAT * D;
    us* hvb   = VTb + (size_t)NP * KP;
    us* headb = hvb + (size_t)M * KP;
    us* tailb = headb + (size_t)M * KP;
    float* P  = (float*)headb;   // 8*40000 fp32 = 1.28 MB aliased over headb+tailb
                                 // (dead before memset; stream order serializes)

    cvt_x<<<(M * D / 4) / 256, 256, 0, stream>>>((const float4*)x, (ushort4*)xb);
    cvt_W<<<(NCAT * D + 255) / 256, 256, 0, stream>>>(Wh, Wt, Wcb);
    reduceU_part<<<dim3((H * H / 4 + 255) / 256, OG), 256, 0, stream>>>(
        (const float4*)U, Wd, (float4*)P);
    cvt_V<<<(NP * KP + 255) / 256, 256, 0, stream>>>(P, VTb);
    hipMemsetAsync(headb, 0, (size_t)2 * M * KP * sizeof(us), stream); // pads head/tail
    hipMemsetAsync(hvb, 0, (size_t)M * KP * sizeof(us), stream);       // pads hv
    proj_mfma<<<dim3(M / 32, NCAT / 16), 64, 0, stream>>>(xb, Wcb, bh, bt, headb, tailb);
    hv_mfma<<<dim3(M / 32, NP / 16), 64, 0, stream>>>(headb, VTb, hvb);
    scores_mfma<<<dim3(S / 32, S / 32, BATCH), 64, 0, stream>>>(hvb, tailb, bd, out);
}